// Round 10
// baseline (340.804 us; speedup 1.0000x reference)
//
#include <hip/hip_runtime.h>
#include <hip/hip_bf16.h>

// Problem constants (fixed by reference): B=4, S=2048, DIN=DOUT=4096
constexpr int GM = 8192;   // B*S rows
constexpr int GN = 4096;   // DOUT
constexpr int GK = 4096;   // DIN

constexpr int BM = 256, BN = 256, BK = 64;
constexpr int NSTEP = GK / BK;   // 64 K-steps
constexpr int IT = NSTEP / 2;    // 32 iterations, 2 K-steps each
constexpr int LDS_BYTES = 2 * (BM + BN) * BK * 2;  // 131072 = 128 KiB

using bf16x8 = __attribute__((ext_vector_type(8))) __bf16;
using f32x16 = __attribute__((ext_vector_type(16))) float;

// -------------------- prep: A = bf16(x * in_scale) --------------------
__global__ __launch_bounds__(256) void prep_x_kernel(
    const float* __restrict__ x, const float* __restrict__ iscale,
    __bf16* __restrict__ A) {
  int e = (blockIdx.x * 256 + threadIdx.x) * 8;  // 8 elems/thread
  float4 v0 = *(const float4*)(x + e);
  float4 v1 = *(const float4*)(x + e + 4);
  int k = e & (GK - 1);
  float4 s0 = *(const float4*)(iscale + k);
  float4 s1 = *(const float4*)(iscale + k + 4);
  bf16x8 o;
  o[0] = (__bf16)(v0.x * s0.x);
  o[1] = (__bf16)(v0.y * s0.y);
  o[2] = (__bf16)(v0.z * s0.z);
  o[3] = (__bf16)(v0.w * s0.w);
  o[4] = (__bf16)(v1.x * s1.x);
  o[5] = (__bf16)(v1.y * s1.y);
  o[6] = (__bf16)(v1.z * s1.z);
  o[7] = (__bf16)(v1.w * s1.w);
  *(bf16x8*)(A + e) = o;
}

// -------------------- prep: Wb = bf16(sign(W)) --------------------
__device__ inline float sgnf(float v) {
  return (float)((v > 0.f) - (v < 0.f));
}

__global__ __launch_bounds__(256) void prep_w_kernel(
    const float* __restrict__ w, __bf16* __restrict__ Wb) {
  int e = (blockIdx.x * 256 + threadIdx.x) * 8;
  float4 v0 = *(const float4*)(w + e);
  float4 v1 = *(const float4*)(w + e + 4);
  bf16x8 o;
  o[0] = (__bf16)sgnf(v0.x);
  o[1] = (__bf16)sgnf(v0.y);
  o[2] = (__bf16)sgnf(v0.z);
  o[3] = (__bf16)sgnf(v0.w);
  o[4] = (__bf16)sgnf(v1.x);
  o[5] = (__bf16)sgnf(v1.y);
  o[6] = (__bf16)sgnf(v1.z);
  o[7] = (__bf16)sgnf(v1.w);
  *(bf16x8*)(Wb + e) = o;
}

// -------------------- GEMM: C[m][n] = sum_k A[m][k]*Wb[n][k] --------------------
// 32x32x16 MFMA port of R8's 8-phase ring. 256x256 tile, BK=64, 512 threads
// (2M x 4N waves, wave tile 128x64 = 4m x 2n frags of 32x32; acc 8 x f32x16).
// LDS: 2 buffers x [A0|A1|B0|B1] x 16 KiB. Per K-step: 4 k-slices (K=16);
// phase p computes slice p (8 independent MFMAs — no adjacent dependent acc
// pairs, unlike the 16x16 kk-inner QUAD). Reads: P1 = slices 0-2 (18 b128),
// P2 = slice 3 (6) -> every region's last read is P2/P6, so R8's stage ring
// and vmcnt(6) retire-set analysis hold verbatim:
//   P1: stage (o):A1 | P3: (n0):B0,B1 | P4: (n0):A0 + vmcnt(6)
//   P5: (n0):A1      | P7: (n1):B0,B1 | P8: (n1):A0 + vmcnt(6)
// (queue at P4/P8: 14 outstanding, retire 8 oldest = exactly the step
// consumed next; prologue stages step0 x4 + step1 {A0,B0,B1}, 14 -> vmcnt(6).)
// Fragment layouts (32x32x16 bf16): A: row=l&31, k=(l>>5)*8+e; B: col=l&31,
// same k; C/D: col=lane&31, row=(reg&3)+8*(reg>>2)+4*(lane>>5) [m74/m101].
// Swizzle (both sides, 0 conflicts R3-R9): 16-B chunk c of row r holds
// K-group c^(r&7); k-group g=(kk*2+(l>>5)) read at chunk g^(l&7).
__device__ inline void gload16(const __bf16* g, const __bf16* l) {
  __builtin_amdgcn_global_load_lds(
      (const __attribute__((address_space(1))) void*)g,
      (__attribute__((address_space(3))) void*)l, 16, 0, 0);
}

#define PHASE_SYNC()                                    \
  __builtin_amdgcn_sched_barrier(0);                    \
  __builtin_amdgcn_s_barrier();                         \
  asm volatile("s_waitcnt lgkmcnt(0)" ::: "memory");    \
  __builtin_amdgcn_sched_barrier(0);                    \
  __builtin_amdgcn_s_setprio(1);

#define PHASE_END()                                     \
  __builtin_amdgcn_s_setprio(0);                        \
  __builtin_amdgcn_sched_barrier(0);                    \
  __builtin_amdgcn_s_barrier();

// one k-slice: 8 independent 32x32x16 MFMAs (acc[mi][nf] all distinct)
#define OCT(KK)                                                              \
  {                                                                          \
    _Pragma("unroll") for (int mi = 0; mi < 4; ++mi)                         \
      _Pragma("unroll") for (int nf = 0; nf < 2; ++nf)                       \
          acc[mi][nf] = __builtin_amdgcn_mfma_f32_32x32x16_bf16(             \
              af[KK][mi], bf[KK][nf], acc[mi][nf], 0, 0, 0);                 \
  }

// read one k-slice's frags from buffer at byte base CB
#define RDSLICE(KK, CB, OFFK)                                                \
  {                                                                          \
    _Pragma("unroll") for (int mi = 0; mi < 4; ++mi)                         \
        af[KK][mi] = *(const bf16x8*)(ldsc + (CB) + abase + mi * 4096 + (OFFK)); \
    _Pragma("unroll") for (int nf = 0; nf < 2; ++nf)                         \
        bf[KK][nf] = *(const bf16x8*)(ldsc + (CB) + bbase + nf * 4096 + (OFFK)); \
  }

__global__ __launch_bounds__(512, 2) void gemm_bt(
    const __bf16* __restrict__ A, const __bf16* __restrict__ B,
    float* __restrict__ C) {
  extern __shared__ __bf16 lds[];  // 2 x 64 KiB buffers

  // Square XCD chunking (FETCH ~200 MB measured R3-R8)
  int bid = blockIdx.x;            // 0..511
  int x = bid & 7, idx = bid >> 3;
  int brow = ((x & 3) << 3) | (idx & 7);   // 0..31
  int bcol = ((x >> 2) << 3) | (idx >> 3); // 0..15

  int tid = threadIdx.x, wid = tid >> 6, lane = tid & 63;
  int wm = wid & 1, wn = wid >> 1;         // 2M x 4N waves
  int l31 = lane & 31, hi = lane >> 5;

  const __bf16* Ab = A + (size_t)(brow * BM) * GK;
  const __bf16* Bb = B + (size_t)(bcol * BN) * GK;
  const __bf16* Ab1 = Ab + (size_t)128 * GK;
  const __bf16* Bb1 = Bb + (size_t)128 * GK;

  // read-side swizzled chunk offsets per k-slice (bytes within 128-B row)
  int xr = lane & 7;
  int offs0 = ((0 + hi) ^ xr) * 16;   // slice 0: k-groups 0,1
  int offs1 = ((2 + hi) ^ xr) * 16;   // slice 1
  int offs2 = ((4 + hi) ^ xr) * 16;   // slice 2
  int offs3 = ((6 + hi) ^ xr) * 16;   // slice 3
  const char* ldsc = (const char*)lds;
  // fragment byte bases within a buffer (regions: A0 0, A1 16K, B0 32K, B1 48K)
  int abase = wm * 16384 + l31 * 128;           // + mi*4096 (32 rows)
  int bbase = 32768 + wn * 8192 + l31 * 128;    // + nf*4096 (32 cols)

  // stage-side: thread t writes bytes [t*16,t*16+16) of each 8-KiB half-region
  int grow = tid >> 3;                         // row within 64-row half
  int gcol = ((tid & 7) ^ (grow & 7)) * 8;     // pre-swizzled source col (elems)

  // stage ONE 128-row half-tile (2 x gload_lds) of K-step `kstep`
  auto STAGE = [&](const __bf16* srcbase, int kstep, int dstelem) {
    const __bf16* s = srcbase + (size_t)grow * GK + kstep * BK + gcol;
    const __bf16* d = lds + dstelem + tid * 8;
    gload16(s, d);
    gload16(s + (size_t)64 * GK, d + 4096);
  };

  f32x16 acc[4][2] = {};
  bf16x8 af[4][4], bf[4][2];  // [k-slice][frag] — all indices compile-time

  // prologue: step0 all 4 halves -> buf0; step1 {A0,B0,B1} -> buf1
  STAGE(Ab, 0, 0);
  STAGE(Ab1, 0, 8192);
  STAGE(Bb, 0, 16384);
  STAGE(Bb1, 0, 24576);
  STAGE(Ab, 1, 32768);        // buf1:A0
  STAGE(Bb, 1, 49152);        // buf1:B0
  STAGE(Bb1, 1, 57344);       // buf1:B1
  asm volatile("s_waitcnt vmcnt(6)" ::: "memory");  // step0 landed
  __builtin_amdgcn_s_barrier();

  for (int j = 0; j < IT; ++j) {
    int o = 2 * j + 1, n0 = 2 * j + 2, n1 = 2 * j + 3;
    bool full = (j < IT - 1);

    // ================= K-step 2j (buf0, byte 0) =================
    // P1: reads slices 0-2 (18); stage (o):A1 -> buf1; MFMA slice 0
    RDSLICE(0, 0, offs0);
    RDSLICE(1, 0, offs1);
    RDSLICE(2, 0, offs2);
    STAGE(Ab1, o, 40960);     // buf1:A1 (last read prev-iter P6; barrier-safe)
    PHASE_SYNC();
    OCT(0);
    PHASE_END();

    // P2: reads slice 3 (6); MFMA slice 1
    RDSLICE(3, 0, offs3);
    PHASE_SYNC();
    OCT(1);
    PHASE_END();

    // P3: stage (n0):B0,B1 -> buf0 (B last read P2); MFMA slice 2
    if (full) { STAGE(Bb, n0, 16384); STAGE(Bb1, n0, 24576); }
    PHASE_SYNC();
    OCT(2);
    PHASE_END();

    // P4: stage (n0):A0 -> buf0 (A last read P2); MFMA slice 3; vmcnt(6)
    if (full) STAGE(Ab, n0, 0);
    PHASE_SYNC();
    OCT(3);
    __builtin_amdgcn_s_setprio(0);
    __builtin_amdgcn_sched_barrier(0);
    if (full) asm volatile("s_waitcnt vmcnt(6)" ::: "memory");
    else      asm volatile("s_waitcnt vmcnt(0)" ::: "memory");
    __builtin_amdgcn_s_barrier();

    // ================= K-step 2j+1 (buf1, byte 65536) =================
    // P5: reads slices 0-2 (18); stage (n0):A1 -> buf0; MFMA slice 0
    RDSLICE(0, 65536, offs0);
    RDSLICE(1, 65536, offs1);
    RDSLICE(2, 65536, offs2);
    if (full) STAGE(Ab1, n0, 8192);
    PHASE_SYNC();
    OCT(0);
    PHASE_END();

    // P6: reads slice 3 (6); MFMA slice 1
    RDSLICE(3, 65536, offs3);
    PHASE_SYNC();
    OCT(1);
    PHASE_END();

    // P7: stage (n1):B0,B1 -> buf1 (B last read P6); MFMA slice 2
    if (full) { STAGE(Bb, n1, 49152); STAGE(Bb1, n1, 57344); }
    PHASE_SYNC();
    OCT(2);
    PHASE_END();

    // P8: stage (n1):A0 -> buf1 (A last read P6); MFMA slice 3; vmcnt(6)
    if (full) STAGE(Ab, n1, 32768);
    PHASE_SYNC();
    OCT(3);
    __builtin_amdgcn_s_setprio(0);
    __builtin_amdgcn_sched_barrier(0);
    if (full) asm volatile("s_waitcnt vmcnt(6)" ::: "memory");
    else      asm volatile("s_waitcnt vmcnt(0)" ::: "memory");
    __builtin_amdgcn_s_barrier();
  }

  // epilogue: C/D 32x32: col = lane&31, row = (reg&3)+8*(reg>>2)+4*(lane>>5)
  int crow0 = brow * BM + wm * 128 + hi * 4;
  int ccol0 = bcol * BN + wn * 64;
#pragma unroll
  for (int mi = 0; mi < 4; ++mi)
#pragma unroll
    for (int nf = 0; nf < 2; ++nf) {
      int col = ccol0 + nf * 32 + l31;
#pragma unroll
      for (int r = 0; r < 16; ++r) {
        int row = crow0 + mi * 32 + (r & 3) + 8 * (r >> 2);
        C[(size_t)row * GN + col] = acc[mi][nf][r];
      }
    }
}

// -------------------- fused out_scale/bias + LayerNorm (in place) --------------------
__global__ __launch_bounds__(256) void ln_fuse(
    float* __restrict__ h, const float* __restrict__ os,
    const float* __restrict__ bs, const float* __restrict__ g,
    const float* __restrict__ be) {
  constexpr int N = GN;  // 4096
  int row = blockIdx.x;
  float* hr = h + (size_t)row * N;
  int t = threadIdx.x;

  float v[16];
  float sum = 0.f, ssq = 0.f;
#pragma unroll
  for (int c = 0; c < 4; ++c) {
    int idx = c * 1024 + t * 4;
    float4 hv = *(const float4*)(hr + idx);
    float4 sv = *(const float4*)(os + idx);
    float4 bv = *(const float4*)(bs + idx);
    float a0 = hv.x * sv.x + bv.x;
    float a1 = hv.y * sv.y + bv.y;
    float a2 = hv.z * sv.z + bv.z;
    float a3 = hv.w * sv.w + bv.w;
    v[c * 4 + 0] = a0; v[c * 4 + 1] = a1; v[c * 4 + 2] = a2; v[c * 4 + 3] = a3;
    sum += a0 + a1 + a2 + a3;
    ssq += a0 * a0 + a1 * a1 + a2 * a2 + a3 * a3;
  }

  // wave64 reduce
#pragma unroll
  for (int off = 32; off > 0; off >>= 1) {
    sum += __shfl_down(sum, off);
    ssq += __shfl_down(ssq, off);
  }
  __shared__ float rs[8];
  int wid = t >> 6, lane = t & 63;
  if (lane == 0) { rs[wid] = sum; rs[4 + wid] = ssq; }
  __syncthreads();
  sum = rs[0] + rs[1] + rs[2] + rs[3];
  ssq = rs[4] + rs[5] + rs[6] + rs[7];

  float mean = sum * (1.f / N);
  float var = ssq * (1.f / N) - mean * mean;
  float rstd = rsqrtf(var + 1e-5f);

#pragma unroll
  for (int c = 0; c < 4; ++c) {
    int idx = c * 1024 + t * 4;
    float4 gv = *(const float4*)(g + idx);
    float4 bev = *(const float4*)(be + idx);
    float4 o;
    o.x = (v[c * 4 + 0] - mean) * rstd * gv.x + bev.x;
    o.y = (v[c * 4 + 1] - mean) * rstd * gv.y + bev.y;
    o.z = (v[c * 4 + 2] - mean) * rstd * gv.z + bev.z;
    o.w = (v[c * 4 + 3] - mean) * rstd * gv.w + bev.w;
    *(float4*)(hr + idx) = o;
  }
}

extern "C" void kernel_launch(void* const* d_in, const int* in_sizes, int n_in,
                              void* d_out, int out_size, void* d_ws, size_t ws_size,
                              hipStream_t stream) {
  const float* x      = (const float*)d_in[0];  // [4,2048,4096]
  const float* w      = (const float*)d_in[1];  // [4096,4096]
  const float* iscale = (const float*)d_in[2];  // [4096]
  const float* oscale = (const float*)d_in[3];  // [4096]
  const float* bias   = (const float*)d_in[4];  // [4096]
  const float* gamma  = (const float*)d_in[5];  // [4096]
  const float* beta   = (const float*)d_in[6];  // [4096]
  float* out = (float*)d_out;                   // [8192,4096] f32

  __bf16* Abf = (__bf16*)d_ws;                                   // 67 MB
  __bf16* Wbf = (__bf16*)((char*)d_ws + (size_t)GM * GK * 2);    // 33.5 MB

  (void)hipFuncSetAttribute((const void*)gemm_bt,
                            hipFuncAttributeMaxDynamicSharedMemorySize, LDS_BYTES);

  prep_x_kernel<<<(GM * GK) / (256 * 8), 256, 0, stream>>>(x, iscale, Abf);
  prep_w_kernel<<<(GN * GK) / (256 * 8), 256, 0, stream>>>(w, Wbf);
  gemm_bt<<<(GM / BM) * (GN / BN), 512, LDS_BYTES, stream>>>(Abf, Wbf, out);
  ln_fuse<<<GM, 256, 0, stream>>>(out, oscale, bias, gamma, beta);
}